// Round 9
// baseline (6688.755 us; speedup 1.0000x reference)
//
#include <hip/hip_runtime.h>
#include <hip/hip_fp16.h>

#define T_TOK 256
#define NNODE 2049
#define HENC  256
#define DHID  512
#define DIN   800
#define G4    1024
#define DG4   2048

typedef _Float16 f16;
typedef _Float16 f16x2 __attribute__((ext_vector_type(2)));
typedef short    bf16x8 __attribute__((ext_vector_type(8)));
typedef float    f32x4  __attribute__((ext_vector_type(4)));

static __device__ __forceinline__ float sigm(float x){ return 1.0f/(1.0f+__expf(-x)); }
static __device__ __forceinline__ float tanhfast(float x){ return 1.0f - 2.0f/(__expf(2.0f*x)+1.0f); }

static __device__ __forceinline__ unsigned short f2bf(float x){
    unsigned u = __builtin_bit_cast(unsigned, x);
    unsigned r = (u + 0x7fffu + ((u>>16)&1u)) >> 16;
    return (unsigned short)r;
}
static __device__ __forceinline__ unsigned packh2(float a, float b){
    f16 ha = (f16)a, hb = (f16)b;
    unsigned short ua = __builtin_bit_cast(unsigned short, ha);
    unsigned short ub = __builtin_bit_cast(unsigned short, hb);
    return (unsigned)ua | ((unsigned)ub << 16);
}
static __device__ __forceinline__ float fdot2(unsigned wpk, unsigned hpk, float c){
#if __has_builtin(__builtin_amdgcn_fdot2)
    return __builtin_amdgcn_fdot2(__builtin_bit_cast(f16x2, wpk),
                                  __builtin_bit_cast(f16x2, hpk), c, false);
#else
    float d;
    asm volatile("v_dot2_f32_f16 %0, %1, %2, %3" : "=v"(d) : "v"(wpk), "v"(hpk), "v"(c));
    return d;
#endif
}

// opaque (non-rematerializable) 16B load
static __device__ __forceinline__ uint4 ldw_opaque(const uint4* p){
    uint4 r;
    asm volatile("global_load_dwordx4 %0, %1, off\n\ts_waitcnt vmcnt(0)"
                 : "=v"(r) : "v"(p));
    return r;
}

// k-major h LDS layout (proven r7): unit n -> physical f16 slot
static __device__ __forceinline__ int hslot(int n){
    return ((((n>>3)&1)*16 + (n>>4))<<3) | (n&7);
}

// circular 16-lane reduction via DPP row_ror (VALU pipe, no LDS)
#define DPP_ADD(A, CTRL) { \
    int _t = __builtin_amdgcn_update_dpp(0, __builtin_bit_cast(int, A), CTRL, 0xF, 0xF, true); \
    A += __builtin_bit_cast(float, _t); }
#define DPP_RED16(A) DPP_ADD(A,0x121) DPP_ADD(A,0x122) DPP_ADD(A,0x124) DPP_ADD(A,0x128)

// ---------------- embedding gather -> bf16 ----------------
__global__ void k_embed(const int* __restrict__ lat,
                        const float* __restrict__ form, const float* __restrict__ lemma,
                        const float* __restrict__ tag,  const float* __restrict__ feats,
                        unsigned short* __restrict__ embB){
    int n = blockIdx.x;
    const int* L = lat + n*11;
    int i0 = L[0], i1 = L[1], i2 = L[2];
    for (int c = threadIdx.x; c < DIN; c += blockDim.x){
        float v;
        if (c < 300)      v = form[i0*300 + c];
        else if (c < 600) v = lemma[i1*300 + (c-300)];
        else if (c < 700) v = tag[i2*100 + (c-600)];
        else {
            float s = 0.f;
            #pragma unroll
            for (int j=0;j<6;++j) s += feats[L[3+j]*100 + (c-700)];
            v = s * (1.0f/6.0f);
        }
        embB[n*DIN + c] = f2bf(v);
    }
}

__global__ void k_f32_to_bf16(const float* __restrict__ src, unsigned short* __restrict__ dst, int n){
    int i = blockIdx.x*blockDim.x + threadIdx.x;
    if (i < n) dst[i] = f2bf(src[i]);
}

// pack Whh (r6/r7 layout, proven): worker b=(d*4+p), thread t: u=t>>4, cq=t&15.
// Gate g, k in {0,1}: uint4 comp c = f16-pair W[g*256+p*64+u][cq*16 + k*8 + 2c .. +1]
// -> wreg4[(b*8 + g*2 + k)*1024 + t]
__global__ void k_pack_whh_v5(const float* __restrict__ wf, const float* __restrict__ wb,
                              uint4* __restrict__ wreg4){
    int id = blockIdx.x*blockDim.x + threadIdx.x;   // 8 blocks x 1024
    int b = id >> 10, t = id & 1023;
    int d = b >> 2, p = b & 3;
    const float* W = d ? wb : wf;
    int u = t >> 4, cq = t & 15;
    for (int g=0; g<4; ++g){
        const float* R = W + (size_t)(g*256 + p*64 + u)*256 + cq*16;
        for (int k=0; k<2; ++k){
            uint4 v;
            v.x = packh2(R[k*8+0], R[k*8+1]);
            v.y = packh2(R[k*8+2], R[k*8+3]);
            v.z = packh2(R[k*8+4], R[k*8+5]);
            v.w = packh2(R[k*8+6], R[k*8+7]);
            wreg4[((size_t)(b*8 + g*2 + k))*1024 + t] = v;
        }
    }
}

// ---------------- bf16 MFMA GEMM: C[M][Nc] = A[M][K] * B[Nc][K]^T (+bias) ----------------
__global__ __launch_bounds__(256) void k_gemm_bf16(const unsigned short* __restrict__ A,
                                                   const unsigned short* __restrict__ B,
                                                   float* __restrict__ C,
                                                   const float* __restrict__ bias,
                                                   int M, int Nc, int K){
    __shared__ unsigned short As[64][40];
    __shared__ unsigned short Bs[64][40];
    int m0 = blockIdx.x*64, n0 = blockIdx.y*64;
    int t = threadIdx.x, w = t>>6, lane = t&63;
    f32x4 acc[4];
    #pragma unroll
    for (int i=0;i<4;++i) acc[i] = (f32x4){0.f,0.f,0.f,0.f};
    int rowl = t>>2, kb0 = (t&3)*8;
    for (int k0=0; k0<K; k0+=32){
        uint4 av;
        int ar = m0 + rowl;
        if (ar < M) av = *(const uint4*)(A + (size_t)ar*K + k0 + kb0);
        else { av.x=av.y=av.z=av.w=0u; }
        *(uint4*)&As[rowl][kb0] = av;
        *(uint4*)&Bs[rowl][kb0] = *(const uint4*)(B + (size_t)(n0+rowl)*K + k0 + kb0);
        __syncthreads();
        int arow = w*16 + (lane&15), kk = (lane>>4)*8;
        bf16x8 af = *(const bf16x8*)&As[arow][kk];
        #pragma unroll
        for (int nt=0;nt<4;++nt){
            bf16x8 bf = *(const bf16x8*)&Bs[nt*16 + (lane&15)][kk];
            acc[nt] = __builtin_amdgcn_mfma_f32_16x16x32_bf16(af, bf, acc[nt], 0,0,0);
        }
        __syncthreads();
    }
    #pragma unroll
    for (int nt=0;nt<4;++nt){
        int col = n0 + nt*16 + (lane&15);
        float bb = bias ? bias[col] : 0.0f;
        #pragma unroll
        for (int r=0;r<4;++r){
            int row = m0 + w*16 + (lane>>4)*4 + r;
            if (row < M) C[(size_t)row*Nc + col] = acc[nt][r] + bb;
        }
    }
}

// ---------------- sequential bi-LSTM scan v9 ----------------
// 8 workers (4/direction), 1024 threads, 8 uint4 weights/thread (proven resident).
// DPP in-register reduction -> cq==0 lane updates c/h directly (no sG phase).
// 2 barriers/step. Flags padded 128B. Gather waves 1-3 spin (s_sleep) concurrently.
#define LOADW(g,k) const uint4 W##g##_##k = ldw_opaque(&wreg4[((size_t)(b*8 + g*2 + k))*1024 + t]);

#define G8(A, P, Q) A = fdot2(P.x,hv0.x,A); A = fdot2(P.y,hv0.y,A); \
                    A = fdot2(P.z,hv0.z,A); A = fdot2(P.w,hv0.w,A); \
                    A = fdot2(Q.x,hv1.x,A); A = fdot2(Q.y,hv1.y,A); \
                    A = fdot2(Q.z,hv1.z,A); A = fdot2(Q.w,hv1.w,A);

__global__ __launch_bounds__(1024)
void k_lstm_scan(const uint4* __restrict__ wreg4,
                 const float* __restrict__ XgF,
                 const float* __restrict__ XgB,
                 int* __restrict__ flg,
                 float* __restrict__ xh,
                 float* __restrict__ encoded,
                 float* __restrict__ h0,
                 float* __restrict__ c0){
    __shared__ uint4 sH4[32];          // 256 h as f16, k-major layout
    int bid = blockIdx.x;
    int d = bid & 7, p = bid >> 3;
    if (d >= 2) return;                // workers: bid 0,8,16,24 (d0) / 1,9,17,25 (d1)
    int b = d*4 + p;
    int t = threadIdx.x;
    int u = t >> 4, cq = t & 15;       // unit u in [0,64), k-chunk cq
    int wv = t >> 6;
    const float* Xg = d ? XgB : XgF;
    unsigned* sH32 = (unsigned*)sH4;
    f16* sHh = (f16*)sH4;

    LOADW(0,0) LOADW(0,1) LOADW(1,0) LOADW(1,1)
    LOADW(2,0) LOADW(2,1) LOADW(3,0) LOADW(3,1)

    if (t < 128) sH32[t] = 0u;
    float c_reg = 0.0f;
    bool upd = (cq == 0);
    __syncthreads();

    int node  = d ? (NNODE-1) : 0;
    int stepd = d ? -1 : 1;
    // partner worker index for gather waves 1..3
    int q  = (wv >= 1 && wv <= 3) ? ((wv-1) + ((wv-1) >= p ? 1 : 0)) : 0;
    int qf = d*4 + q;

    for (int s=0; s<NNODE; ++s){
        // update lanes prefetch their unit's 4 gate-x inputs
        float xi=0.f, xf=0.f, xgg=0.f, xo=0.f;
        if (upd){
            const float* xr = Xg + (size_t)node*G4 + p*64 + u;
            xi  = xr[0];
            xf  = xr[256];
            xgg = xr[512];
            xo  = xr[768];
        }
        uint4 hv0 = sH4[cq];
        uint4 hv1 = sH4[cq + 16];
        float a0=0.f,a1=0.f,a2=0.f,a3=0.f;
        G8(a0, W0_0, W0_1)
        G8(a1, W1_0, W1_1)
        G8(a2, W2_0, W2_1)
        G8(a3, W3_0, W3_1)
        DPP_RED16(a0)
        DPP_RED16(a1)
        DPP_RED16(a2)
        DPP_RED16(a3)
        if (upd){
            float gi = a0 + xi, gf = a1 + xf, gg = a2 + xgg, go = a3 + xo;
            float c = sigm(gf)*c_reg + sigm(gi)*tanhfast(gg);
            c_reg = c;
            float h = sigm(go)*tanhfast(c);
            __hip_atomic_store(&xh[((b*2) + (s&1))*64 + u], h,
                               __ATOMIC_RELAXED, __HIP_MEMORY_SCOPE_AGENT);
            sHh[hslot(p*64 + u)] = (f16)h;
            encoded[(size_t)node*DHID + d*HENC + p*64 + u] = h;
            if (s == NNODE-1){ h0[d*HENC + p*64 + u] = h; c0[d*HENC + p*64 + u] = c; }
        }
        __syncthreads();               // A: every wave's xh stores drained (vmcnt0 + barrier)
        if (t == 0){
            __hip_atomic_store(&flg[b*32], s+1, __ATOMIC_RELEASE, __HIP_MEMORY_SCOPE_AGENT);
        } else if (wv >= 1 && wv <= 3){
            long iters = 0;
            while (__hip_atomic_load(&flg[qf*32], __ATOMIC_ACQUIRE, __HIP_MEMORY_SCOPE_AGENT) < s+1){
                __builtin_amdgcn_s_sleep(1);
                if (++iters > (1L<<22)) break;         // safety valve vs. hang
            }
            float hp = xh[(qf*2 + (s&1))*64 + (t&63)];
            sHh[hslot(q*64 + (t&63))] = (f16)hp;
        }
        __syncthreads();               // D: full h ready for next step
        node += stepd;
    }
}

// Kd = dec_whh @ h0 + dec_b
__global__ void k_dec_const(const float* __restrict__ dec_whh, const float* __restrict__ dec_b,
                            const float* __restrict__ h0, float* __restrict__ Kd){
    __shared__ float sh[512];
    int t = threadIdx.x;
    int r = blockIdx.x*256 + t;
    sh[t] = h0[t]; sh[256+t] = h0[256+t];
    __syncthreads();
    float a = 0.f;
    const float* Wr = dec_whh + (size_t)r*512;
    for (int k=0;k<512;++k) a += Wr[k]*sh[k];
    Kd[r] = a + dec_b[r];
}

// decoder h for every possible ptr node
__global__ void k_hall(const float* __restrict__ G, const float* __restrict__ Kd,
                       const float* __restrict__ c0, float* __restrict__ Hall){
    int n = blockIdx.x, u = threadIdx.x;
    const float* g = G + (size_t)n*DG4;
    float gi = g[u]        + Kd[u];
    float gf = g[512+u]    + Kd[512+u];
    float gg = g[1024+u]   + Kd[1024+u];
    float go = g[1536+u]   + Kd[1536+u];
    float c  = sigm(gf)*c0[u] + sigm(gi)*tanhfast(gg);
    Hall[(size_t)n*DHID + u] = sigm(go)*tanhfast(c);
}

// S[i][p][c] = encoded[cand(i,c)] . Hall[prev(i,p)]
__global__ __launch_bounds__(256) void k_scores(const float* __restrict__ encoded,
                                                const float* __restrict__ Hall,
                                                float* __restrict__ S){
    __shared__ float sE[8][512];
    __shared__ float sHp[8][512];
    int i = blockIdx.x, t = threadIdx.x;
    for (int idx = t; idx < 8*512; idx += 256){
        int r = idx >> 9, c = idx & 511;
        int cand = 1 + i*8 + r;
        sE[r][c] = encoded[(size_t)cand*DHID + c];
        int prev = (i==0) ? 0 : (1 + (i-1)*8 + r);
        sHp[r][c] = Hall[(size_t)prev*DHID + c];
    }
    __syncthreads();
    int w = t>>6, lane = t&63;
    for (int q=0;q<16;++q){
        int pi = w*16 + q, p = pi>>3, c = pi&7;
        float v = 0.f;
        #pragma unroll
        for (int j=0;j<8;++j) v += sE[c][lane*8+j]*sHp[p][lane*8+j];
        #pragma unroll
        for (int off=32; off; off>>=1) v += __shfl_xor(v, off);
        if (lane==0) S[i*64 + p*8 + c] = v;
    }
}

// sequential pointer chain + loss
__global__ __launch_bounds__(256) void k_decode(const float* __restrict__ S, float* __restrict__ out){
    __shared__ float nll[2048];
    __shared__ int   cst[2048];
    __shared__ int   path[256];
    __shared__ float wsum[4];
    int t = threadIdx.x;
    for (int p=0;p<8;++p){
        const float* s = S + t*64 + p*8;
        float m = s[0]; int am = 0;
        #pragma unroll
        for (int c=1;c<8;++c){ float v = s[c]; if (v > m){ m = v; am = c; } }
        float e = 0.f;
        #pragma unroll
        for (int c=0;c<8;++c) e += __expf(s[c]-m);
        float lse = m + __logf(e);
        nll[t*8+p] = lse - s[0];
        cst[t*8+p] = am;
    }
    __syncthreads();
    if (t == 0){
        int p = 0;
        for (int i=0;i<256;++i){
            int idx = i*8 + p;
            path[i] = idx;
            int c = cst[idx];
            out[i+1] = (float)(1 + i*8 + c);
            p = c;
        }
        out[0] = 0.0f;
    }
    __syncthreads();
    float v = nll[path[t]];
    #pragma unroll
    for (int off=32; off; off>>=1) v += __shfl_xor(v, off);
    if ((t&63)==0) wsum[t>>6] = v;
    __syncthreads();
    if (t==0) out[257] = (wsum[0]+wsum[1]+wsum[2]+wsum[3]) * (1.0f/256.0f);
}

extern "C" void kernel_launch(void* const* d_in, const int* in_sizes, int n_in,
                              void* d_out, int out_size, void* d_ws, size_t ws_size,
                              hipStream_t stream){
    (void)in_sizes; (void)n_in; (void)out_size; (void)ws_size;
    const int*   lattice  = (const int*)  d_in[0];
    const float* form     = (const float*)d_in[2];
    const float* lemma    = (const float*)d_in[3];
    const float* tag      = (const float*)d_in[4];
    const float* feats    = (const float*)d_in[5];
    const float* wih_f    = (const float*)d_in[6];
    const float* whh_f    = (const float*)d_in[7];
    const float* b_f      = (const float*)d_in[8];
    const float* wih_b    = (const float*)d_in[9];
    const float* whh_b    = (const float*)d_in[10];
    const float* b_b      = (const float*)d_in[11];
    const float* dwih     = (const float*)d_in[12];
    const float* dwhh     = (const float*)d_in[13];
    const float* db       = (const float*)d_in[14];
    float* out = (float*)d_out;

    char* ws = (char*)d_ws;
    size_t o = 0;
    auto alloc = [&](size_t bytes)->char*{ char* p = ws + o; o = (o + bytes + 255) & ~(size_t)255; return p; };
    int*            flg    = (int*)alloc(1024);                     // 8 flags, 128B apart
    float*          xh     = (float*)alloc(8*2*64*4);               // [8][2][64] f32
    unsigned short* embB   = (unsigned short*)alloc((size_t)NNODE*DIN*2);
    unsigned short* wihfB  = (unsigned short*)alloc((size_t)G4*DIN*2);
    unsigned short* wihbB  = (unsigned short*)alloc((size_t)G4*DIN*2);
    unsigned short* dwihB  = (unsigned short*)alloc((size_t)DG4*DIN*2);
    uint4*          wreg4  = (uint4*)alloc((size_t)8*8*1024*16);
    float*          XgF    = (float*)alloc((size_t)NNODE*G4*4);
    float*          XgB    = (float*)alloc((size_t)NNODE*G4*4);
    float*          Graw   = (float*)alloc((size_t)NNODE*DG4*4);
    float*          enc    = (float*)alloc((size_t)NNODE*DHID*4);
    float*          h0     = (float*)alloc(512*4);
    float*          c0     = (float*)alloc(512*4);
    float*          Kd     = (float*)alloc(2048*4);
    float*          Hall   = (float*)alloc((size_t)NNODE*DHID*4);
    float*          Sbuf   = (float*)alloc((size_t)256*64*4);

    // reset sync state every launch (graph-capture safe)
    hipMemsetAsync(d_ws, 0, 8192, stream);

    k_f32_to_bf16<<<(G4*DIN+255)/256, 256, 0, stream>>>(wih_f, wihfB, G4*DIN);
    k_f32_to_bf16<<<(G4*DIN+255)/256, 256, 0, stream>>>(wih_b, wihbB, G4*DIN);
    k_f32_to_bf16<<<(DG4*DIN+255)/256, 256, 0, stream>>>(dwih, dwihB, DG4*DIN);
    k_pack_whh_v5<<<8, 1024, 0, stream>>>(whh_f, whh_b, wreg4);
    k_embed<<<NNODE, 256, 0, stream>>>(lattice, form, lemma, tag, feats, embB);

    dim3 gE((NNODE+63)/64, G4/64);
    k_gemm_bf16<<<gE, 256, 0, stream>>>(embB, wihfB, XgF, b_f, NNODE, G4, DIN);
    k_gemm_bf16<<<gE, 256, 0, stream>>>(embB, wihbB, XgB, b_b, NNODE, G4, DIN);
    dim3 gD((NNODE+63)/64, DG4/64);
    k_gemm_bf16<<<gD, 256, 0, stream>>>(embB, dwihB, Graw, nullptr, NNODE, DG4, DIN);

    k_lstm_scan<<<32, 1024, 0, stream>>>(wreg4, XgF, XgB, flg, xh, enc, h0, c0);

    k_dec_const<<<8, 256, 0, stream>>>(dwhh, db, h0, Kd);
    k_hall<<<NNODE, 512, 0, stream>>>(Graw, Kd, c0, Hall);
    k_scores<<<256, 256, 0, stream>>>(enc, Hall, Sbuf);
    k_decode<<<1, 256, 0, stream>>>(Sbuf, out);
}

// Round 10
// 4966.768 us; speedup vs baseline: 1.3467x; 1.3467x over previous
//
#include <hip/hip_runtime.h>
#include <hip/hip_fp16.h>

#define T_TOK 256
#define NNODE 2049
#define HENC  256
#define DHID  512
#define DIN   800
#define G4    1024
#define DG4   2048

typedef _Float16 f16;
typedef _Float16 f16x2 __attribute__((ext_vector_type(2)));
typedef short    bf16x8 __attribute__((ext_vector_type(8)));
typedef float    f32x4  __attribute__((ext_vector_type(4)));

static __device__ __forceinline__ float sigm(float x){ return 1.0f/(1.0f+__expf(-x)); }
static __device__ __forceinline__ float tanhfast(float x){ return 1.0f - 2.0f/(__expf(2.0f*x)+1.0f); }

static __device__ __forceinline__ unsigned short f2bf(float x){
    unsigned u = __builtin_bit_cast(unsigned, x);
    unsigned r = (u + 0x7fffu + ((u>>16)&1u)) >> 16;
    return (unsigned short)r;
}
static __device__ __forceinline__ unsigned packh2(float a, float b){
    f16 ha = (f16)a, hb = (f16)b;
    unsigned short ua = __builtin_bit_cast(unsigned short, ha);
    unsigned short ub = __builtin_bit_cast(unsigned short, hb);
    return (unsigned)ua | ((unsigned)ub << 16);
}
static __device__ __forceinline__ float fdot2(unsigned wpk, unsigned hpk, float c){
#if __has_builtin(__builtin_amdgcn_fdot2)
    return __builtin_amdgcn_fdot2(__builtin_bit_cast(f16x2, wpk),
                                  __builtin_bit_cast(f16x2, hpk), c, false);
#else
    float d;
    asm volatile("v_dot2_f32_f16 %0, %1, %2, %3" : "=v"(d) : "v"(wpk), "v"(hpk), "v"(c));
    return d;
#endif
}

// opaque (non-rematerializable) 16B global load
static __device__ __forceinline__ uint4 ldw_opaque(const uint4* p){
    uint4 r;
    asm volatile("global_load_dwordx4 %0, %1, off\n\ts_waitcnt vmcnt(0)"
                 : "=v"(r) : "v"(p));
    return r;
}

// h LDS layout v10: logical uint4 i (h dwords 4i..4i+3) at physical (i&7)*4 + (i>>3)
static __device__ __forceinline__ int ph10(int i){ return (i&7)*4 + (i>>3); }
// f16 slot for unit n
static __device__ __forceinline__ int hs10(int n){ return ph10(n>>3)*8 + (n&7); }

// DPP reduction over 8-lane group (cq): xor1, xor2 (quad_perm), then half-row mirror
#define DPPA(A, CTRL) { \
    int _t = __builtin_amdgcn_update_dpp(0, __builtin_bit_cast(int, A), CTRL, 0xF, 0xF, true); \
    A += __builtin_bit_cast(float, _t); }
#define RED8(A) DPPA(A,0xB1) DPPA(A,0x4E) DPPA(A,0x141)

// volatile LDS pair-read (can't be hoisted -> no register-lifetime blowup)
#define LDSW(R0, R1, BASE, O0, O1) \
    asm volatile("ds_read_b128 %0, %2 offset:" O0 "\n\t" \
                 "ds_read_b128 %1, %2 offset:" O1 "\n\t" \
                 "s_waitcnt lgkmcnt(0)" \
                 : "=&v"(R0), "=&v"(R1) : "v"(BASE));

// 8 fdot2 of one gate-half: weight uint4 pair (P,Q) vs h uint4 pair (H0,H1)
#define GP(A, P, Q, H0, H1) \
    A = fdot2(P.x,H0.x,A); A = fdot2(P.y,H0.y,A); A = fdot2(P.z,H0.z,A); A = fdot2(P.w,H0.w,A); \
    A = fdot2(Q.x,H1.x,A); A = fdot2(Q.y,H1.y,A); A = fdot2(Q.z,H1.z,A); A = fdot2(Q.w,H1.w,A);

// ---------------- embedding gather -> bf16 ----------------
__global__ void k_embed(const int* __restrict__ lat,
                        const float* __restrict__ form, const float* __restrict__ lemma,
                        const float* __restrict__ tag,  const float* __restrict__ feats,
                        unsigned short* __restrict__ embB){
    int n = blockIdx.x;
    const int* L = lat + n*11;
    int i0 = L[0], i1 = L[1], i2 = L[2];
    for (int c = threadIdx.x; c < DIN; c += blockDim.x){
        float v;
        if (c < 300)      v = form[i0*300 + c];
        else if (c < 600) v = lemma[i1*300 + (c-300)];
        else if (c < 700) v = tag[i2*100 + (c-600)];
        else {
            float s = 0.f;
            #pragma unroll
            for (int j=0;j<6;++j) s += feats[L[3+j]*100 + (c-700)];
            v = s * (1.0f/6.0f);
        }
        embB[n*DIN + c] = f2bf(v);
    }
}

__global__ void k_f32_to_bf16(const float* __restrict__ src, unsigned short* __restrict__ dst, int n){
    int i = blockIdx.x*blockDim.x + threadIdx.x;
    if (i < n) dst[i] = f2bf(src[i]);
}

// pack Whh v7: worker b=(d*2+p) in [0,4), thread t: u=t>>3, cq=t&7.
// Gate g: row = g*256 + p*128 + u, col chunk = cq*32 .. +31.
//   wregA[(b*8+g*2+k)*1024+t] : cols k*8   .. k*8+7    (k=0,1)  -> registers
//   wldsB[(b*8+g*2+k)*1024+t] : cols 16+k*8 .. 16+k*8+7 (k=0,1) -> LDS
__global__ void k_pack_whh_v7(const float* __restrict__ wf, const float* __restrict__ wb,
                              uint4* __restrict__ wregA, uint4* __restrict__ wldsB){
    int b = blockIdx.x, t = threadIdx.x;
    int d = b >> 1, p = b & 1;
    const float* W = d ? wb : wf;
    int u = t >> 3, cq = t & 7;
    for (int g=0; g<4; ++g){
        const float* R = W + (size_t)(g*256 + p*128 + u)*256 + cq*32;
        for (int k=0; k<2; ++k){
            uint4 v;
            v.x = packh2(R[k*8+0], R[k*8+1]);
            v.y = packh2(R[k*8+2], R[k*8+3]);
            v.z = packh2(R[k*8+4], R[k*8+5]);
            v.w = packh2(R[k*8+6], R[k*8+7]);
            wregA[((size_t)(b*8 + g*2 + k))*1024 + t] = v;
            v.x = packh2(R[16+k*8+0], R[16+k*8+1]);
            v.y = packh2(R[16+k*8+2], R[16+k*8+3]);
            v.z = packh2(R[16+k*8+4], R[16+k*8+5]);
            v.w = packh2(R[16+k*8+6], R[16+k*8+7]);
            wldsB[((size_t)(b*8 + g*2 + k))*1024 + t] = v;
        }
    }
}

// ---------------- bf16 MFMA GEMM: C[M][Nc] = A[M][K] * B[Nc][K]^T (+bias) ----------------
__global__ __launch_bounds__(256) void k_gemm_bf16(const unsigned short* __restrict__ A,
                                                   const unsigned short* __restrict__ B,
                                                   float* __restrict__ C,
                                                   const float* __restrict__ bias,
                                                   int M, int Nc, int K){
    __shared__ unsigned short As[64][40];
    __shared__ unsigned short Bs[64][40];
    int m0 = blockIdx.x*64, n0 = blockIdx.y*64;
    int t = threadIdx.x, w = t>>6, lane = t&63;
    f32x4 acc[4];
    #pragma unroll
    for (int i=0;i<4;++i) acc[i] = (f32x4){0.f,0.f,0.f,0.f};
    int rowl = t>>2, kb0 = (t&3)*8;
    for (int k0=0; k0<K; k0+=32){
        uint4 av;
        int ar = m0 + rowl;
        if (ar < M) av = *(const uint4*)(A + (size_t)ar*K + k0 + kb0);
        else { av.x=av.y=av.z=av.w=0u; }
        *(uint4*)&As[rowl][kb0] = av;
        *(uint4*)&Bs[rowl][kb0] = *(const uint4*)(B + (size_t)(n0+rowl)*K + k0 + kb0);
        __syncthreads();
        int arow = w*16 + (lane&15), kk = (lane>>4)*8;
        bf16x8 af = *(const bf16x8*)&As[arow][kk];
        #pragma unroll
        for (int nt=0;nt<4;++nt){
            bf16x8 bf = *(const bf16x8*)&Bs[nt*16 + (lane&15)][kk];
            acc[nt] = __builtin_amdgcn_mfma_f32_16x16x32_bf16(af, bf, acc[nt], 0,0,0);
        }
        __syncthreads();
    }
    #pragma unroll
    for (int nt=0;nt<4;++nt){
        int col = n0 + nt*16 + (lane&15);
        float bb = bias ? bias[col] : 0.0f;
        #pragma unroll
        for (int r=0;r<4;++r){
            int row = m0 + w*16 + (lane>>4)*4 + r;
            if (row < M) C[(size_t)row*Nc + col] = acc[nt][r] + bb;
        }
    }
}

// ---------------- sequential bi-LSTM scan v10 ----------------
// 4 workers (2/dir, pairwise same-XCD exchange). 1024 threads.
// Weights: 8 uint4/thread in VGPR + 8 uint4/thread in LDS (128 KB dynamic).
// Thread (u=t>>3, cq=t&7) computes all 4 gates of unit u over cols cq*32..+31;
// DPP 8-lane reduce; lane cq==0 updates c/h.
#define LOADW(g,k) const uint4 W##g##_##k = ldw_opaque(&wregA[((size_t)(wk*8 + g*2 + k))*1024 + t]);

__global__ __launch_bounds__(1024)
void k_lstm_scan(const uint4* __restrict__ wregA,
                 const uint4* __restrict__ wldsB,
                 const float* __restrict__ XgF,
                 const float* __restrict__ XgB,
                 int* __restrict__ flg,
                 float* __restrict__ xh,
                 float* __restrict__ encoded,
                 float* __restrict__ h0,
                 float* __restrict__ c0){
    extern __shared__ char smem[];
    uint4* sW  = (uint4*)smem;                 // 8*1024 uint4 = 128 KB
    uint4* sH4 = (uint4*)(smem + 131072);      // 32 uint4 = 512 B (full 256-h as f16)
    unsigned* sH32 = (unsigned*)sH4;
    f16* sHh = (f16*)sH4;

    int bid = blockIdx.x;
    int d = bid & 7, p = bid >> 3;
    if (d >= 2) return;                        // workers: bid 0,8 (d0) / 1,9 (d1)
    int wk  = d*2 + p;
    int pwk = d*2 + (1-p);
    int t = threadIdx.x;
    int u = t >> 3, cq = t & 7;
    int wv = t >> 6, l = t & 63;
    bool upd = (cq == 0);
    const float* Xg = d ? XgB : XgF;

    LOADW(0,0) LOADW(0,1) LOADW(1,0) LOADW(1,1)
    LOADW(2,0) LOADW(2,1) LOADW(3,0) LOADW(3,1)

    #pragma unroll
    for (int k8=0; k8<8; ++k8) sW[k8*1024 + t] = wldsB[((size_t)(wk*8 + k8))*1024 + t];
    if (t < 128) sH32[t] = 0u;
    float c_reg = 0.0f;
    __syncthreads();

    unsigned baseA = (unsigned)(size_t)(&sW[t]);
    unsigned baseB = baseA + 65536u;
    int ih0 = ph10(cq*4+0), ih1 = ph10(cq*4+1), ih2 = ph10(cq*4+2), ih3 = ph10(cq*4+3);

    int node  = d ? (NNODE-1) : 0;
    int stepd = d ? -1 : 1;

    for (int s=0; s<NNODE; ++s){
        float xi=0.f, xf=0.f, xgg=0.f, xo=0.f;
        if (upd){
            const float* xr = Xg + (size_t)node*G4 + p*128 + u;
            xi  = xr[0];
            xf  = xr[256];
            xgg = xr[512];
            xo  = xr[768];
        }
        float a0=0.f,a1=0.f,a2=0.f,a3=0.f;
        {   // phase 1: register weight halves vs h chunks 0,1
            uint4 hv0 = sH4[ih0];
            uint4 hv1 = sH4[ih1];
            GP(a0, W0_0, W0_1, hv0, hv1)
            GP(a1, W1_0, W1_1, hv0, hv1)
            GP(a2, W2_0, W2_1, hv0, hv1)
            GP(a3, W3_0, W3_1, hv0, hv1)
        }
        {   // phase 2: LDS weight halves vs h chunks 2,3
            uint4 hv2 = sH4[ih2];
            uint4 hv3 = sH4[ih3];
            uint4 L0, L1;
            LDSW(L0, L1, baseA, "0", "16384")       GP(a0, L0, L1, hv2, hv3)
            LDSW(L0, L1, baseA, "32768", "49152")   GP(a1, L0, L1, hv2, hv3)
            LDSW(L0, L1, baseB, "0", "16384")       GP(a2, L0, L1, hv2, hv3)
            LDSW(L0, L1, baseB, "32768", "49152")   GP(a3, L0, L1, hv2, hv3)
        }
        RED8(a0) RED8(a1) RED8(a2) RED8(a3)
        if (upd){
            float gi = a0 + xi, gf = a1 + xf, gg = a2 + xgg, go = a3 + xo;
            float c = sigm(gf)*c_reg + sigm(gi)*tanhfast(gg);
            c_reg = c;
            float h = sigm(go)*tanhfast(c);
            xh[(wk*2 + (s&1))*128 + u] = h;
            sHh[hs10(p*128 + u)] = (f16)h;
            encoded[(size_t)node*DHID + d*HENC + p*128 + u] = h;
            if (s == NNODE-1){ h0[d*HENC + p*128 + u] = h; c0[d*HENC + p*128 + u] = c; }
        }
        __syncthreads();                           // A: all waves' stores drained
        if (t == 0){
            __hip_atomic_store(&flg[wk*32], s+1, __ATOMIC_RELEASE, __HIP_MEMORY_SCOPE_AGENT);
        } else if (wv == 1){
            long iters = 0;
            while (__hip_atomic_load(&flg[pwk*32], __ATOMIC_ACQUIRE, __HIP_MEMORY_SCOPE_AGENT) < s+1){
                if (++iters > (1L<<27)) break;     // safety valve vs. hang
            }
            float2 hp = *(const float2*)&xh[(pwk*2 + (s&1))*128 + 2*l];
            int n_abs = (1-p)*128 + 2*l;
            sH32[(ph10(n_abs>>3)<<2) | ((n_abs&7)>>1)] = packh2(hp.x, hp.y);
        }
        __syncthreads();                           // D: full h ready for next step
        node += stepd;
    }
}

// Kd = dec_whh @ h0 + dec_b
__global__ void k_dec_const(const float* __restrict__ dec_whh, const float* __restrict__ dec_b,
                            const float* __restrict__ h0, float* __restrict__ Kd){
    __shared__ float sh[512];
    int t = threadIdx.x;
    int r = blockIdx.x*256 + t;
    sh[t] = h0[t]; sh[256+t] = h0[256+t];
    __syncthreads();
    float a = 0.f;
    const float* Wr = dec_whh + (size_t)r*512;
    for (int k=0;k<512;++k) a += Wr[k]*sh[k];
    Kd[r] = a + dec_b[r];
}

// decoder h for every possible ptr node
__global__ void k_hall(const float* __restrict__ G, const float* __restrict__ Kd,
                       const float* __restrict__ c0, float* __restrict__ Hall){
    int n = blockIdx.x, u = threadIdx.x;
    const float* g = G + (size_t)n*DG4;
    float gi = g[u]        + Kd[u];
    float gf = g[512+u]    + Kd[512+u];
    float gg = g[1024+u]   + Kd[1024+u];
    float go = g[1536+u]   + Kd[1536+u];
    float c  = sigm(gf)*c0[u] + sigm(gi)*tanhfast(gg);
    Hall[(size_t)n*DHID + u] = sigm(go)*tanhfast(c);
}

// S[i][p][c] = encoded[cand(i,c)] . Hall[prev(i,p)]
__global__ __launch_bounds__(256) void k_scores(const float* __restrict__ encoded,
                                                const float* __restrict__ Hall,
                                                float* __restrict__ S){
    __shared__ float sE[8][512];
    __shared__ float sHp[8][512];
    int i = blockIdx.x, t = threadIdx.x;
    for (int idx = t; idx < 8*512; idx += 256){
        int r = idx >> 9, c = idx & 511;
        int cand = 1 + i*8 + r;
        sE[r][c] = encoded[(size_t)cand*DHID + c];
        int prev = (i==0) ? 0 : (1 + (i-1)*8 + r);
        sHp[r][c] = Hall[(size_t)prev*DHID + c];
    }
    __syncthreads();
    int w = t>>6, lane = t&63;
    for (int q=0;q<16;++q){
        int pi = w*16 + q, p = pi>>3, c = pi&7;
        float v = 0.f;
        #pragma unroll
        for (int j=0;j<8;++j) v += sE[c][lane*8+j]*sHp[p][lane*8+j];
        #pragma unroll
        for (int off=32; off; off>>=1) v += __shfl_xor(v, off);
        if (lane==0) S[i*64 + p*8 + c] = v;
    }
}

// sequential pointer chain + loss
__global__ __launch_bounds__(256) void k_decode(const float* __restrict__ S, float* __restrict__ out){
    __shared__ float nll[2048];
    __shared__ int   cst[2048];
    __shared__ int   path[256];
    __shared__ float wsum[4];
    int t = threadIdx.x;
    for (int p=0;p<8;++p){
        const float* s = S + t*64 + p*8;
        float m = s[0]; int am = 0;
        #pragma unroll
        for (int c=1;c<8;++c){ float v = s[c]; if (v > m){ m = v; am = c; } }
        float e = 0.f;
        #pragma unroll
        for (int c=0;c<8;++c) e += __expf(s[c]-m);
        float lse = m + __logf(e);
        nll[t*8+p] = lse - s[0];
        cst[t*8+p] = am;
    }
    __syncthreads();
    if (t == 0){
        int p = 0;
        for (int i=0;i<256;++i){
            int idx = i*8 + p;
            path[i] = idx;
            int c = cst[idx];
            out[i+1] = (float)(1 + i*8 + c);
            p = c;
        }
        out[0] = 0.0f;
    }
    __syncthreads();
    float v = nll[path[t]];
    #pragma unroll
    for (int off=32; off; off>>=1) v += __shfl_xor(v, off);
    if ((t&63)==0) wsum[t>>6] = v;
    __syncthreads();
    if (t==0) out[257] = (wsum[0]+wsum[1]+wsum[2]+wsum[3]) * (1.0f/256.0f);
}

extern "C" void kernel_launch(void* const* d_in, const int* in_sizes, int n_in,
                              void* d_out, int out_size, void* d_ws, size_t ws_size,
                              hipStream_t stream){
    (void)in_sizes; (void)n_in; (void)out_size; (void)ws_size;
    const int*   lattice  = (const int*)  d_in[0];
    const float* form     = (const float*)d_in[2];
    const float* lemma    = (const float*)d_in[3];
    const float* tag      = (const float*)d_in[4];
    const float* feats    = (const float*)d_in[5];
    const float* wih_f    = (const float*)d_in[6];
    const float* whh_f    = (const float*)d_in[7];
    const float* b_f      = (const float*)d_in[8];
    const float* wih_b    = (const float*)d_in[9];
    const float* whh_b    = (const float*)d_in[10];
    const float* b_b      = (const float*)d_in[11];
    const float* dwih     = (const float*)d_in[12];
    const float* dwhh     = (const float*)d_in[13];
    const float* db       = (const float*)d_in[14];
    float* out = (float*)d_out;

    char* ws = (char*)d_ws;
    size_t o = 0;
    auto alloc = [&](size_t bytes)->char*{ char* p = ws + o; o = (o + bytes + 255) & ~(size_t)255; return p; };
    int*            flg    = (int*)alloc(512);                      // 4 flags, 128B apart
    float*          xh     = (float*)alloc(4*2*128*4);              // [4][2][128] f32
    unsigned short* embB   = (unsigned short*)alloc((size_t)NNODE*DIN*2);
    unsigned short* wihfB  = (unsigned short*)alloc((size_t)G4*DIN*2);
    unsigned short* wihbB  = (unsigned short*)alloc((size_t)G4*DIN*2);
    unsigned short* dwihB  = (unsigned short*)alloc((size_t)DG4*DIN*2);
    uint4*          wregA  = (uint4*)alloc((size_t)4*8*1024*16);
    uint4*          wldsB  = (uint4*)alloc((size_t)4*8*1024*16);
    float*          XgF    = (float*)alloc((size_t)NNODE*G4*4);
    float*          XgB    = (float*)alloc((size_t)NNODE*G4*4);
    float*          Graw   = (float*)alloc((size_t)NNODE*DG4*4);
    float*          enc    = (float*)alloc((size_t)NNODE*DHID*4);
    float*          h0     = (float*)alloc(512*4);
    float*          c0     = (float*)alloc(512*4);
    float*          Kd     = (float*)alloc(2048*4);
    float*          Hall   = (float*)alloc((size_t)NNODE*DHID*4);
    float*          Sbuf   = (float*)alloc((size_t)256*64*4);

    const int scan_lds = 131072 + 1024;
    hipFuncSetAttribute(reinterpret_cast<const void*>(k_lstm_scan),
                        hipFuncAttributeMaxDynamicSharedMemorySize, scan_lds);

    // reset sync state every launch (graph-capture safe)
    hipMemsetAsync(d_ws, 0, 8192, stream);

    k_f32_to_bf16<<<(G4*DIN+255)/256, 256, 0, stream>>>(wih_f, wihfB, G4*DIN);
    k_f32_to_bf16<<<(G4*DIN+255)/256, 256, 0, stream>>>(wih_b, wihbB, G4*DIN);
    k_f32_to_bf16<<<(DG4*DIN+255)/256, 256, 0, stream>>>(dwih, dwihB, DG4*DIN);
    k_pack_whh_v7<<<4, 1024, 0, stream>>>(whh_f, whh_b, wregA, wldsB);
    k_embed<<<NNODE, 256, 0, stream>>>(lattice, form, lemma, tag, feats, embB);

    dim3 gE((NNODE+63)/64, G4/64);
    k_gemm_bf16<<<gE, 256, 0, stream>>>(embB, wihfB, XgF, b_f, NNODE, G4, DIN);
    k_gemm_bf16<<<gE, 256, 0, stream>>>(embB, wihbB, XgB, b_b, NNODE, G4, DIN);
    dim3 gD((NNODE+63)/64, DG4/64);
    k_gemm_bf16<<<gD, 256, 0, stream>>>(embB, dwihB, Graw, nullptr, NNODE, DG4, DIN);

    k_lstm_scan<<<16, 1024, scan_lds, stream>>>(wregA, wldsB, XgF, XgB, flg, xh, enc, h0, c0);

    k_dec_const<<<8, 256, 0, stream>>>(dwhh, db, h0, Kd);
    k_hall<<<NNODE, 512, 0, stream>>>(Graw, Kd, c0, Hall);
    k_scores<<<256, 256, 0, stream>>>(enc, Hall, Sbuf);
    k_decode<<<1, 256, 0, stream>>>(Sbuf, out);
}